// Round 14
// baseline (43.457 us; speedup 1.0000x reference)
//
#include <hip/hip_runtime.h>
#include <stdint.h>

// out[b,p] = mean_d( probes[p,d] <= X[b,d] ? 1.0 : X[b,d] )
// B=2048, P=512, D=256, f32. Exact-mask math (validated R6-R13):
//   q1 = fma(p,-2^24,1)            exact odd int
//   m  = clamp(pk_fma(x, 2^24, q1)) = clamp(2^24(x-p)+1) in {0,1}, 1 iff p<=x
//   y  = 1-x (exact);  acc += m*y;  quarter partial = (64 - Sum y) + Sum m*y
//   out = Sum_quarters / 256
// R14 structure: NO LDS in the compute path. Threads stream xv/pv quads
// directly from global (L2-resident: inputs 2.5MB << 4MB/XCD; per-block
// traffic = tile bytes, coalescer merges the 8-way lane duplication).
// 1024 blocks x 256 thr (4 blocks/CU, 16 waves/CU), 32b x 32p tile,
// 4 waves = 4 d-quarters. LDS only for the 16KB combine buffer.

#define BATCH  2048
#define NPROBE 512
#define DIM    256
#define KF 16777216.0f

typedef float f4 __attribute__((ext_vector_type(4)));
typedef float f2 __attribute__((ext_vector_type(2)));

__global__ __launch_bounds__(256, 4)
void yoneda_kernel(const float* __restrict__ X, const float* __restrict__ Pr,
                   float* __restrict__ out) {
  __shared__ float cb[4096];          // combine only: 16 KB -> 4 blocks/CU

  const int tid = threadIdx.x;
  const int p0 = blockIdx.x * 32, b0 = blockIdx.y * 32;
  const int w  = tid >> 6;            // wave = d-quarter (64 d = 16 quads)
  const int tb = (tid >> 3) & 7;      // rows tb+8i, i<4
  const int tp = tid & 7;             // cols tp+8j, j<4

  const float* xb[4];
  const float* pb[4];
  #pragma unroll
  for (int i = 0; i < 4; ++i) {
    xb[i] = X  + (size_t)(b0 + tb + 8 * i) * DIM + w * 64;
    pb[i] = Pr + (size_t)(p0 + tp + 8 * i) * DIM + w * 64;
  }

  f2 acc2[4][4], accy2[4];
  #pragma unroll
  for (int i = 0; i < 4; ++i) {
    accy2[i] = (f2){0.0f, 0.0f};
    #pragma unroll
    for (int j = 0; j < 4; ++j) acc2[i][j] = (f2){0.0f, 0.0f};
  }
  const f2 K2   = {KF, KF};
  const f2 mK2  = {-KF, -KF};
  const f2 one2 = {1.0f, 1.0f};

  #pragma unroll 4
  for (int s = 0; s < 16; ++s) {      // quad within the d-quarter
    f2 qa[4], qc[4];
    #pragma unroll
    for (int j = 0; j < 4; ++j) {     // pv load + q1 transform (exact)
      f4 p = *(const f4*)(pb[j] + 4 * s);
      f2 pa = {p[0], p[1]}, pc = {p[2], p[3]};
      asm("v_pk_fma_f32 %0, %1, %2, %3"
          : "=v"(qa[j]) : "v"(pa), "v"(mK2), "v"(one2));
      asm("v_pk_fma_f32 %0, %1, %2, %3"
          : "=v"(qc[j]) : "v"(pc), "v"(mK2), "v"(one2));
    }
    #pragma unroll
    for (int i = 0; i < 4; ++i) {
      f4 xv = *(const f4*)(xb[i] + 4 * s);
      f2 xa = {xv[0], xv[1]}, xc = {xv[2], xv[3]};
      f2 ya = one2 - xa;              // exact
      f2 yc = one2 - xc;
      accy2[i] += ya;
      accy2[i] += yc;
      #pragma unroll
      for (int j = 0; j < 4; ++j) {
        f2 ma, mc;
        asm("v_pk_fma_f32 %0, %1, %2, %3 clamp"
            : "=v"(ma) : "v"(xa), "v"(K2), "v"(qa[j]));
        asm("v_pk_fma_f32 %0, %1, %2, %0"
            : "+v"(acc2[i][j]) : "v"(ma), "v"(ya));
        asm("v_pk_fma_f32 %0, %1, %2, %3 clamp"
            : "=v"(mc) : "v"(xc), "v"(K2), "v"(qc[j]));
        asm("v_pk_fma_f32 %0, %1, %2, %0"
            : "+v"(acc2[i][j]) : "v"(mc), "v"(yc));
      }
    }
  }

  // ---- combine 4 d-quarter partials via 16 KB LDS.
  // slot = o*4 + (w ^ (tb&3)): write phase = 32 banks x 2 lanes (free);
  // read = b128 stride-16B (canonical). Fixed per-o sum order -> deterministic.
  #pragma unroll
  for (int i = 0; i < 4; ++i) {
    float sxp = 64.0f - (accy2[i][0] + accy2[i][1]);   // Sum_quarter x
    #pragma unroll
    for (int j = 0; j < 4; ++j) {
      int o = (tb + 8 * i) * 32 + tp + 8 * j;
      cb[o * 4 + (w ^ (tb & 3))] = sxp + acc2[i][j][0] + acc2[i][j][1];
    }
  }
  __syncthreads();
  const float inv = 1.0f / 256.0f;
  #pragma unroll
  for (int k = 0; k < 4; ++k) {
    int o = tid + 256 * k;
    f4 v4 = *(const f4*)&cb[o * 4];
    float v = ((v4[0] + v4[1]) + (v4[2] + v4[3])) * inv;
    int row = o >> 5, col = o & 31;
    out[(size_t)(b0 + row) * NPROBE + p0 + col] = v;
  }
}

extern "C" void kernel_launch(void* const* d_in, const int* in_sizes, int n_in,
                              void* d_out, int out_size, void* d_ws, size_t ws_size,
                              hipStream_t stream) {
  const float* X  = (const float*)d_in[0];   // (2048, 256) f32
  const float* Pr = (const float*)d_in[1];   // (512, 256)  f32
  float* outp = (float*)d_out;               // (2048, 512) f32
  dim3 grid(NPROBE / 32, BATCH / 32);        // (16, 64) = 1024 blocks, 4/CU
  yoneda_kernel<<<grid, 256, 0, stream>>>(X, Pr, outp);
}